// Round 6
// baseline (48.076 us; speedup 1.0000x reference)
//
#include <hip/hip_runtime.h>
#include <math.h>

// Problem constants (verified against setup_inputs): E=1024, CTX=1024.
#define EDIM 1024
#define CTXDIM 1024
#define H2 2048
#define NBLK 256

// ws float layout:
//   [0    : 1024)  h first half  = C * relu(emb[x] @ Mw^T + Mb)
//   [1024 : 2048)  h second half = sum_c relu(emb[ctx] @ Mw^T + Mb)
//   [2048 : 3072)  mu
//   [3072 : 4096)  sigma
//   [4096 : 4099)  3 unsigned counters (bar0, bar1, finale) — memset to 0
//   [4100 : ...)   S: S[0]=logdet, S[1]=S_x, S[2..2+C)=pos, S[2+C..)=neg
//
// Cross-block data moves ONLY via agent-scope atomic load/store (coherent at
// the device coherence point once retired; __syncthreads drains vmcnt before
// the arrival RMW). NO cache-maintenance fences anywhere — round 4 showed
// per-thread agent fences cost ~20 ns each serialized (8192 of them = 160 µs).

#define AST(p, v) __hip_atomic_store((p), (v), __ATOMIC_RELAXED, __HIP_MEMORY_SCOPE_AGENT)
#define ALD(p)    __hip_atomic_load((p), __ATOMIC_RELAXED, __HIP_MEMORY_SCOPE_AGENT)

__device__ __forceinline__ void grid_bar(unsigned* c) {
    __syncthreads();                       // all waves' stores drained (vmcnt 0)
    if (threadIdx.x == 0) {
        __hip_atomic_fetch_add(c, 1u, __ATOMIC_RELEASE, __HIP_MEMORY_SCOPE_AGENT);
        while (__hip_atomic_load(c, __ATOMIC_RELAXED, __HIP_MEMORY_SCOPE_AGENT)
               < (unsigned)NBLK)
            __builtin_amdgcn_s_sleep(2);
    }
    __syncthreads();
}

__global__ __launch_bounds__(1024) void k_fused(
    const float* __restrict__ emb, const float* __restrict__ Mw,
    const float* __restrict__ Mb, const float* __restrict__ Uw,
    const float* __restrict__ Ub, const float* __restrict__ Ww,
    const float* __restrict__ Wb, const float* __restrict__ pmu,
    const float* __restrict__ psig, const int* __restrict__ x,
    const int* __restrict__ ctx, const int* __restrict__ negs,
    int C, int CN, int NEG, int KDIM,
    float* __restrict__ ws, float* __restrict__ out)
{
    __shared__ int    idxs[64];
    __shared__ float  pacc[16];
    __shared__ float  pxs[4];
    __shared__ float4 hbuf4[512];          // h (2048 f32)
    __shared__ float4 ms4[512];            // mu (256 f4) then sigma (256 f4)
    __shared__ int    winflag;

    const int tid  = threadIdx.x;
    const int w    = tid >> 6;
    const int lane = tid & 63;
    const int b    = blockIdx.x;
    unsigned* cnt  = (unsigned*)(ws + 4096);
    float* Sbuf    = ws + 4100;
    float* hbuf    = (float*)hbuf4;
    float* musig   = (float*)ms4;

    // ---------------- Phase A: h[2048] ----------------
    // Block owns 4 cols; wave (c,g) = col 4b+c, rows r ≡ g (mod 4) of 1+C rows.
    {
        if (tid <= C) idxs[tid] = (tid == 0) ? x[0] : ctx[tid - 1];
        const int c = w & 3;
        const int g = w >> 2;
        const int j = b * 4 + c;
        const float4* mrow = (const float4*)(Mw + (size_t)j * EDIM);
        const float4 mw0 = mrow[lane];
        const float4 mw1 = mrow[lane + 64];
        const float4 mw2 = mrow[lane + 128];
        const float4 mw3 = mrow[lane + 192];
        const float bj = Mb[j];
        __syncthreads();

        float acc = 0.f, px = 0.f;
#pragma unroll 2
        for (int r = g; r <= C; r += 4) {
            const int idx = idxs[r];
            const float4* e4 = (const float4*)(emb + (size_t)idx * EDIM);
            const float4 a  = e4[lane];
            const float4 bb = e4[lane + 64];
            const float4 d  = e4[lane + 128];
            const float4 e  = e4[lane + 192];
            float s = a.x*mw0.x + a.y*mw0.y + a.z*mw0.z + a.w*mw0.w;
            s += bb.x*mw1.x + bb.y*mw1.y + bb.z*mw1.z + bb.w*mw1.w;
            s += d.x*mw2.x + d.y*mw2.y + d.z*mw2.z + d.w*mw2.w;
            s += e.x*mw3.x + e.y*mw3.y + e.z*mw3.z + e.w*mw3.w;
#pragma unroll
            for (int m = 32; m >= 1; m >>= 1) s += __shfl_xor(s, m);
            const float v = fmaxf(s + bj, 0.f);
            if (r == 0) px = (float)C * v;   // x-row appears only in group 0
            else        acc += v;
        }
        if (lane == 0) {
            pacc[w] = acc;
            if (g == 0) pxs[c] = px;
        }
        __syncthreads();
        if (tid < 4) {
            const int jj = b * 4 + tid;
            AST(&ws[jj], pxs[tid]);
            AST(&ws[CTXDIM + jj],
                pacc[tid] + pacc[tid + 4] + pacc[tid + 8] + pacc[tid + 12]);
        }
    }

    grid_bar(&cnt[0]);

    // ---------------- Phase B: mu, sigma ----------------
    // 16 waves: 8 rows/block, 2 waves/row (half each of the 2048-dot).
    {
        hbuf[tid]        = ALD(&ws[tid]);
        hbuf[tid + 1024] = ALD(&ws[tid + 1024]);
        __syncthreads();

        const int row  = b * 8 + (w >> 1);           // 0..2047
        const int half = w & 1;
        const bool is_mu = (row < CTXDIM);
        const int rr = row & (CTXDIM - 1);
        const float4* W4 = (const float4*)((is_mu ? Uw : Ww) + (size_t)rr * H2)
                           + half * 256;
        const float4* h4 = hbuf4 + half * 256;
        float s = 0.f;
#pragma unroll
        for (int k = 0; k < 4; ++k) {
            const float4 wv = W4[lane + 64 * k];
            const float4 hv = h4[lane + 64 * k];
            s += wv.x*hv.x + wv.y*hv.y + wv.z*hv.z + wv.w*hv.w;
        }
#pragma unroll
        for (int m = 32; m >= 1; m >>= 1) s += __shfl_xor(s, m);
        if (lane == 0) pacc[w] = s;
        __syncthreads();
        if (half == 0 && lane == 0) {
            const float tot = pacc[w] + pacc[w + 1];
            if (is_mu) {
                AST(&ws[2048 + rr], tot + Ub[rr]);
            } else {
                const float v = tot + Wb[rr];
                AST(&ws[3072 + rr], fmaxf(v, 0.f) + log1pf(expf(-fabsf(v))));
            }
        }
    }

    grid_bar(&cnt[1]);

    // ---------------- Phase C: per-candidate S + fused finale ----------------
    // Task t = b + 256*w for w<3. t0: logdet; t1: x; [2,2+C): pos; rest: neg.
    {
        musig[tid]        = ALD(&ws[2048 + tid]);
        musig[tid + 1024] = ALD(&ws[3072 + tid]);
        __syncthreads();

        const int ntask = 2 + C + CN;
        const int t = b + NBLK * w;
        if (w < 3 && t < ntask) {
            float acc = 0.f;
            if (t == 0) {          // logdet = sum log sigma
#pragma unroll
                for (int k = 0; k < 16; ++k) acc += logf(musig[1024 + lane + 64 * k]);
            } else {
                int idx;
                if (t == 1)          idx = idxs[0];
                else if (t < 2 + C)  idx = idxs[t - 1];
                else                 idx = negs[t - 2 - C];
                const float4* m4 = (const float4*)(pmu  + (size_t)idx * CTXDIM);
                const float4* s4 = (const float4*)(psig + (size_t)idx * CTXDIM);
#pragma unroll
                for (int k = 0; k < 4; ++k) {
                    const int i = lane + 64 * k;
                    const float4 m  = m4[i];
                    const float4 sv = s4[i];
                    const float4 mu = ms4[i];
                    const float4 sg = ms4[256 + i];
                    { const float s2 = sv.x*sv.x; const float dd = m.x-mu.x; acc += (sg.x + dd*dd)/s2 + logf(s2); }
                    { const float s2 = sv.y*sv.y; const float dd = m.y-mu.y; acc += (sg.y + dd*dd)/s2 + logf(s2); }
                    { const float s2 = sv.z*sv.z; const float dd = m.z-mu.z; acc += (sg.z + dd*dd)/s2 + logf(s2); }
                    { const float s2 = sv.w*sv.w; const float dd = m.w-mu.w; acc += (sg.w + dd*dd)/s2 + logf(s2); }
                }
            }
#pragma unroll
            for (int m = 32; m >= 1; m >>= 1) acc += __shfl_xor(acc, m);
            if (lane == 0) AST(&Sbuf[t], acc);
        }

        __syncthreads();            // drain all task stores in this block
        if (tid == 0) {
            const unsigned old = __hip_atomic_fetch_add(&cnt[2], 1u,
                                   __ATOMIC_RELEASE, __HIP_MEMORY_SCOPE_AGENT);
            winflag = (old == (unsigned)(NBLK - 1));
        }
        __syncthreads();
        if (winflag && w == 0) {    // last-arriving block, wave 0: finale
            float lik = 0.f;
            for (int i = lane; i < CN; i += 64) {
                const float sn = ALD(&Sbuf[2 + C + i]);
                const float sp = ALD(&Sbuf[2 + i / NEG]);
                lik += fmaxf(0.f, 0.5f * (sn - sp) + 1.0f);   // kl_neg - kl_pos + 1
            }
#pragma unroll
            for (int m = 32; m >= 1; m >>= 1) lik += __shfl_xor(lik, m);
            if (lane == 0) {
                const float ld = ALD(&Sbuf[0]);
                const float sx = ALD(&Sbuf[1]);
                out[0] = lik - 0.5f * (sx - (float)KDIM - ld);  // - kl_prior
            }
        }
    }
}

extern "C" void kernel_launch(void* const* d_in, const int* in_sizes, int n_in,
                              void* d_out, int out_size, void* d_ws, size_t ws_size,
                              hipStream_t stream) {
    const int*   x    = (const int*)d_in[0];
    const int*   ctx  = (const int*)d_in[1];
    const int*   negs = (const int*)d_in[2];
    const float* emb  = (const float*)d_in[3];
    const float* Mw   = (const float*)d_in[4];
    const float* Mb   = (const float*)d_in[5];
    const float* Uw   = (const float*)d_in[6];
    const float* Ub   = (const float*)d_in[7];
    const float* Ww   = (const float*)d_in[8];
    const float* Wb   = (const float*)d_in[9];
    const float* pmu  = (const float*)d_in[10];
    const float* psig = (const float*)d_in[11];
    float* ws  = (float*)d_ws;
    float* out = (float*)d_out;

    const int C    = in_sizes[1];          // 50
    const int CN   = in_sizes[2];          // 500
    const int NEG  = CN / C;               // 10
    const int KDIM = in_sizes[5];          // CTX = 1024

    // Re-zero the 3 barrier counters each launch (poison-safe, graph-legal).
    (void)hipMemsetAsync((char*)d_ws + 4096 * sizeof(float), 0,
                         3 * sizeof(unsigned), stream);
    k_fused<<<NBLK, 1024, 0, stream>>>(emb, Mw, Mb, Uw, Ub, Ww, Wb, pmu, psig,
                                       x, ctx, negs, C, CN, NEG, KDIM, ws, out);
}

// Round 7
// 30.189 us; speedup vs baseline: 1.5925x; 1.5925x over previous
//
#include <hip/hip_runtime.h>
#include <math.h>

// Problem constants (verified against setup_inputs): E=1024, CTX=1024.
#define EDIM 1024
#define CTXDIM 1024
#define H2 2048

// ws float layout:
//   [0    : 1024)  h first half  = C * relu(emb[x] @ Mw^T + Mb)
//   [1024 : 2048)  h second half = sum_c relu(emb[ctx] @ Mw^T + Mb)
//   [4096]         (unsigned) k_tail arrival counter   (zeroed by k_h blk 0)
//   [4100 : ...)   Sbuf: [0]=logdet, [1]=S_x, [2..2+C)=pos, [2+C..2+C+CN)=neg
//                  accumulated via device-scope float atomicAdd (zeroed by k_h)

#define ALD(p) __hip_atomic_load((p), __ATOMIC_RELAXED, __HIP_MEMORY_SCOPE_AGENT)

// ---------------- Kernel 1: h[2048] ----------------
// 256 blocks x 1024 thr (16 waves). Block owns 4 cols; wave (c,g) = col 4b+c,
// rows r ≡ g (mod 4) of the 1+C input rows (row 0 = x). ctx indices preloaded
// into LDS so the row loop has no dependent global scalar loads.
// Block 0 additionally zeroes the counter + Sbuf for k_tail (runs before it
// in stream order; kernel boundary guarantees visibility).
__global__ __launch_bounds__(1024) void k_h(
    const float* __restrict__ emb, const float* __restrict__ Mw,
    const float* __restrict__ Mb, const int* __restrict__ x,
    const int* __restrict__ ctx, int C, int CN, float* __restrict__ ws)
{
    __shared__ int   idxs[64];
    __shared__ float pacc[16];
    __shared__ float pxs[4];
    const int tid  = threadIdx.x;
    const int w    = tid >> 6;
    const int lane = tid & 63;
    const int c    = w & 3;
    const int g    = w >> 2;
    const int j    = blockIdx.x * 4 + c;

    if (blockIdx.x == 0 && tid < 8 + 2 + C + CN)   // counter pad + Sbuf
        ws[4096 + tid] = 0.f;
    if (tid <= C) idxs[tid] = (tid == 0) ? x[0] : ctx[tid - 1];

    const float4* mrow = (const float4*)(Mw + (size_t)j * EDIM);
    const float4 mw0 = mrow[lane];
    const float4 mw1 = mrow[lane + 64];
    const float4 mw2 = mrow[lane + 128];
    const float4 mw3 = mrow[lane + 192];
    const float bj = Mb[j];
    __syncthreads();

    float acc = 0.f, px = 0.f;
#pragma unroll 2
    for (int r = g; r <= C; r += 4) {
        const int idx = idxs[r];
        const float4* e4 = (const float4*)(emb + (size_t)idx * EDIM);
        const float4 a  = e4[lane];
        const float4 bb = e4[lane + 64];
        const float4 d  = e4[lane + 128];
        const float4 e  = e4[lane + 192];
        float s = a.x*mw0.x + a.y*mw0.y + a.z*mw0.z + a.w*mw0.w;
        s += bb.x*mw1.x + bb.y*mw1.y + bb.z*mw1.z + bb.w*mw1.w;
        s += d.x*mw2.x + d.y*mw2.y + d.z*mw2.z + d.w*mw2.w;
        s += e.x*mw3.x + e.y*mw3.y + e.z*mw3.z + e.w*mw3.w;
#pragma unroll
        for (int m = 32; m >= 1; m >>= 1) s += __shfl_xor(s, m);
        const float v = fmaxf(s + bj, 0.f);
        if (r == 0) px = (float)C * v;   // x-row appears only in group 0
        else        acc += v;
    }
    if (lane == 0) {
        pacc[w] = acc;
        if (g == 0) pxs[c] = px;
    }
    __syncthreads();
    if (tid < 4) {
        const int jj = blockIdx.x * 4 + tid;
        ws[jj]          = pxs[tid];
        ws[CTXDIM + jj] = pacc[tid] + pacc[tid + 4] + pacc[tid + 8] + pacc[tid + 12];
    }
}

// ---------------- Kernel 2: mu/sigma (column slice) + S partials + finale ----
// 128 blocks x 1024 thr. Block b owns columns i = 8b..8b+7:
//   waves 0..7  : mu_i   = dot(Uw[i], h) + Ub[i]
//   waves 8..15 : sig_i  = softplus(dot(Ww[i], h) + Wb[i])
// Then thread t < 551 computes the 8-column partial of S(task t) and does one
// device-scope float atomicAdd; thread 551 adds the logdet partial.
// Last-arriving block's wave 0 computes the hinge sum + final scalar.
__global__ __launch_bounds__(1024) void k_tail(
    const float* __restrict__ Uw, const float* __restrict__ Ub,
    const float* __restrict__ Ww, const float* __restrict__ Wb,
    const float* __restrict__ pmu, const float* __restrict__ psig,
    const int* __restrict__ x, const int* __restrict__ ctx,
    const int* __restrict__ negs, int C, int CN, int NEG, int KDIM,
    int nblk, float* __restrict__ ws, float* __restrict__ out)
{
    __shared__ float4 hbuf4[512];          // h (2048 f32)
    __shared__ float  msig[16];            // [0:8) mu, [8:16) sigma (this block's cols)
    __shared__ int    winflag;
    const int tid  = threadIdx.x;
    const int w    = tid >> 6;
    const int lane = tid & 63;
    const int b    = blockIdx.x;           // owns cols 8b..8b+7
    float* Sbuf    = ws + 4100;
    unsigned* cnt  = (unsigned*)(ws + 4096);

    // Early gather issue: each KL-task thread pulls its 8 prior columns now;
    // the loads complete under the GEMV work below.
    const int nkl = 1 + C + CN;            // 551
    float4 gm0, gm1, gs0, gs1;
    if (tid < nkl) {
        const int idx = (tid == 0) ? x[0]
                       : (tid <= C ? ctx[tid - 1] : negs[tid - 1 - C]);
        const float4* m4 = (const float4*)(pmu  + (size_t)idx * CTXDIM + 8 * b);
        const float4* s4 = (const float4*)(psig + (size_t)idx * CTXDIM + 8 * b);
        gm0 = m4[0]; gm1 = m4[1];
        gs0 = s4[0]; gs1 = s4[1];
    }

    if (tid < 512) hbuf4[tid] = ((const float4*)ws)[tid];
    __syncthreads();

    // GEMV: one wave per (mu|sigma) row.
    {
        const int colw = w & 7;
        const int i = 8 * b + colw;
        const float4* W4 = (const float4*)(((w < 8) ? Uw : Ww) + (size_t)i * H2);
        float s = 0.f;
#pragma unroll
        for (int k = 0; k < 8; ++k) {
            const float4 wv = W4[lane + 64 * k];
            const float4 hv = hbuf4[lane + 64 * k];
            s += wv.x*hv.x + wv.y*hv.y + wv.z*hv.z + wv.w*hv.w;
        }
#pragma unroll
        for (int m = 32; m >= 1; m >>= 1) s += __shfl_xor(s, m);
        if (lane == 0) {
            if (w < 8) {
                msig[colw] = s + Ub[i];
            } else {
                const float v = s + Wb[i];
                msig[8 + colw] = fmaxf(v, 0.f) + log1pf(expf(-fabsf(v)));  // softplus
            }
        }
    }
    __syncthreads();

    // Per-task 8-column partials -> one atomicAdd each.
    if (tid < nkl) {
        const float mu0 = msig[0], mu1 = msig[1], mu2 = msig[2], mu3 = msig[3];
        const float mu4 = msig[4], mu5 = msig[5], mu6 = msig[6], mu7 = msig[7];
        const float sg0 = msig[8], sg1 = msig[9], sg2 = msig[10], sg3 = msig[11];
        const float sg4 = msig[12], sg5 = msig[13], sg6 = msig[14], sg7 = msig[15];
        float acc = 0.f;
        { const float s2 = gs0.x*gs0.x; const float d = gm0.x - mu0; acc += (sg0 + d*d)/s2 + logf(s2); }
        { const float s2 = gs0.y*gs0.y; const float d = gm0.y - mu1; acc += (sg1 + d*d)/s2 + logf(s2); }
        { const float s2 = gs0.z*gs0.z; const float d = gm0.z - mu2; acc += (sg2 + d*d)/s2 + logf(s2); }
        { const float s2 = gs0.w*gs0.w; const float d = gm0.w - mu3; acc += (sg3 + d*d)/s2 + logf(s2); }
        { const float s2 = gs1.x*gs1.x; const float d = gm1.x - mu4; acc += (sg4 + d*d)/s2 + logf(s2); }
        { const float s2 = gs1.y*gs1.y; const float d = gm1.y - mu5; acc += (sg5 + d*d)/s2 + logf(s2); }
        { const float s2 = gs1.z*gs1.z; const float d = gm1.z - mu6; acc += (sg6 + d*d)/s2 + logf(s2); }
        { const float s2 = gs1.w*gs1.w; const float d = gm1.w - mu7; acc += (sg7 + d*d)/s2 + logf(s2); }
        atomicAdd(&Sbuf[1 + tid], acc);            // slot: x->1, pos c->2+c, neg n->2+C+n
    } else if (tid == nkl) {
        float ld = 0.f;
#pragma unroll
        for (int jj = 0; jj < 8; ++jj) ld += logf(msig[8 + jj]);
        atomicAdd(&Sbuf[0], ld);                   // logdet partial
    }

    __syncthreads();                // block's atomics drained (vmcnt 0)
    if (tid == 0) {
        const unsigned old = __hip_atomic_fetch_add(cnt, 1u,
                               __ATOMIC_RELEASE, __HIP_MEMORY_SCOPE_AGENT);
        winflag = (old == (unsigned)(nblk - 1));
    }
    __syncthreads();
    if (winflag && w == 0) {        // last-arriving block, wave 0
        __builtin_amdgcn_fence(__ATOMIC_ACQUIRE, "agent");   // one inv, one wave
        float lik = 0.f;
        for (int i = lane; i < CN; i += 64) {
            const float sn = ALD(&Sbuf[2 + C + i]);
            const float sp = ALD(&Sbuf[2 + i / NEG]);
            lik += fmaxf(0.f, 0.5f * (sn - sp) + 1.0f);   // kl_neg - kl_pos + 1
        }
#pragma unroll
        for (int m = 32; m >= 1; m >>= 1) lik += __shfl_xor(lik, m);
        if (lane == 0) {
            const float ld = ALD(&Sbuf[0]);
            const float sx = ALD(&Sbuf[1]);
            out[0] = lik - 0.5f * (sx - (float)KDIM - ld);  // - kl_prior
        }
    }
}

extern "C" void kernel_launch(void* const* d_in, const int* in_sizes, int n_in,
                              void* d_out, int out_size, void* d_ws, size_t ws_size,
                              hipStream_t stream) {
    const int*   x    = (const int*)d_in[0];
    const int*   ctx  = (const int*)d_in[1];
    const int*   negs = (const int*)d_in[2];
    const float* emb  = (const float*)d_in[3];
    const float* Mw   = (const float*)d_in[4];
    const float* Mb   = (const float*)d_in[5];
    const float* Uw   = (const float*)d_in[6];
    const float* Ub   = (const float*)d_in[7];
    const float* Ww   = (const float*)d_in[8];
    const float* Wb   = (const float*)d_in[9];
    const float* pmu  = (const float*)d_in[10];
    const float* psig = (const float*)d_in[11];
    float* ws  = (float*)d_ws;
    float* out = (float*)d_out;

    const int C    = in_sizes[1];          // 50
    const int CN   = in_sizes[2];          // 500
    const int NEG  = CN / C;               // 10
    const int KDIM = in_sizes[5];          // CTX = 1024

    k_h<<<CTXDIM / 4, 1024, 0, stream>>>(emb, Mw, Mb, x, ctx, C, CN, ws);
    k_tail<<<CTXDIM / 8, 1024, 0, stream>>>(Uw, Ub, Ww, Wb, pmu, psig,
                                            x, ctx, negs, C, CN, NEG, KDIM,
                                            CTXDIM / 8, ws, out);
}